// Round 8
// baseline (361.681 us; speedup 1.0000x reference)
//
#include <hip/hip_runtime.h>

// Problem constants: B=2, t=5, C=16, G=64
#define G3_    (64 * 64 * 64)          // 262144
#define CCH    16
#define TT     5
#define LSTRIDE 17                      // padded LDS x-stride (cols 0..16)
#define BUF    4096                     // floats: single LDS buffer (max idx 3841)
#define NCHB   4                        // channels per warp block (round-3 optimum)
#define NWARP  (4096 * (CCH / NCHB))    // 16384 warp blocks (tile x channel-group)
#define NCOPY  8192
#define NBLK   (NWARP + NCOPY)          // 24576 = 8 * 3072

// ---------------------------------------------------------------------------
// Round-8 (from round-7 @156.9us fused = round-3 parity; VALU 38%, occ 70%,
// conflicts 12.9M). Cycle accounting says the LDS pipe is the top consumer
// (~60% busy: 320 LDS wave-instrs/block + 50K conflict cyc/CU); the rest of
// the gap is the per-channel vmcnt-drain + barrier chain. Two cuts:
//  1. MINIMAL ZERO-INIT. Proof from the bbox: for any sample with nonzero
//     weight, X0 <= xhi-1 (max_ix bound), so corner +1/+17 reads stay in the
//     staged region; only weight-0 clamped reads escape, and they touch
//     exactly {col sxe of each staged row} u {tail [sz*lstep, sz*lstep+17)}.
//     Zero only those (~2 writes/thread vs 16): -20% LDS wave-instrs, and
//     the prologue drops to ONE barrier (zero/stage same-slot overlap only
//     on weight-0 slots, both values finite -> benign race).
//  2. 2-DEEP REGISTER PREFETCH (stgA/stgB): write phase for ch c+1 waits
//     vmcnt(8) with ch c+2's loads in flight -> each staged load gets a full
//     extra channel phase to land. VGPR 32 -> ~50 (must stay <=64 for 8
//     waves/SIMD; NOT forced via launch_bounds -- round-1 spill lesson).
// Kept: NCHB=4 (round-4 proved longer chains kill block-TLP), x-pair outputs
// + fused float2 store, ds_read2 corner reads + low-edge weight swap,
// even-aligned float2 staging, hoisted coeff kernel, 2:1 copy interleave,
// XCD-contiguous swizzle.
// ---------------------------------------------------------------------------

// Setup kernel: per pose n -> {ax,bx,cx, ay,by,cy, az,bz,cz, kx,ky,kz}.
__global__ void coeff_kernel(const float* __restrict__ cam, float* __restrict__ Tc)
{
    int n = threadIdx.x;
    if (n >= 8) return;
    int b = n >> 2, j = n & 3;
    const float* p0 = cam + (size_t)(b * TT) * 16;
    const float* p1 = cam + (size_t)(b * TT + j + 1) * 16;
    float a00 = p0[0], a01 = p0[1], a02 = p0[2],  at0 = p0[3];
    float a10 = p0[4], a11 = p0[5], a12 = p0[6],  at1 = p0[7];
    float a20 = p0[8], a21 = p0[9], a22 = p0[10], at2 = p0[11];
    float b00 = p1[0], b01 = p1[1], b02 = p1[2],  bt0 = p1[3];
    float b10 = p1[4], b11 = p1[5], b12 = p1[6],  bt1 = p1[7];
    float b20 = p1[8], b21 = p1[9], b22 = p1[10], bt2 = p1[11];
    // T = P0 * inv(P1), rigid: R = R0*R1^T, tr = t0 - R*t1.
    float R00 = a00*b00 + a01*b01 + a02*b02;
    float R01 = a00*b10 + a01*b11 + a02*b12;
    float R02 = a00*b20 + a01*b21 + a02*b22;
    float R10 = a10*b00 + a11*b01 + a12*b02;
    float R11 = a10*b10 + a11*b11 + a12*b12;
    float R12 = a10*b20 + a11*b21 + a12*b22;
    float R20 = a20*b00 + a21*b01 + a22*b02;
    float R21 = a20*b10 + a21*b11 + a22*b12;
    float R22 = a20*b20 + a21*b21 + a22*b22;
    float trx = at0 - (R00*bt0 + R01*bt1 + R02*bt2);
    float try_= at1 - (R10*bt0 + R11*bt1 + R12*bt2);
    float trz = at2 - (R20*bt0 + R21*bt1 + R22*bt2);

    const float S  = 1.0f / 64.0f;
    const float SC = 32.0f / 0.4921875f;
    float ax = SC * R00 * S, bx = SC * R01 * S, cx = SC * R02 * S;
    float ay = SC * R10 * S, by = SC * R11 * S, cy = SC * R12 * S;
    float az = SC * R20 * S, bz = SC * R21 * S, cz = SC * R22 * S;
    float* o = Tc + n * 12;
    o[0] = ax; o[1] = bx; o[2] = cx;
    o[3] = ay; o[4] = by; o[5] = cy;
    o[6] = az; o[7] = bz; o[8] = cz;
    o[9]  = -31.5f * (ax + bx + cx) + SC * trx + 31.5f;
    o[10] = -31.5f * (ay + by + cy) + SC * try_ + 31.5f;
    o[11] = -31.5f * (az + bz + cz) + SC * trz + 31.5f;
}

__global__ __launch_bounds__(256) void fused_kernel(const float* __restrict__ vox,
                                                    const float* __restrict__ Tc,
                                                    float* __restrict__ out)
{
    __shared__ float lds[BUF];                          // 16 KB
    const int tid = threadIdx.x;

    // XCD-contiguous bijective swizzle (24576 % 8 == 0).
    const int bid  = blockIdx.x;
    const int sbid = (bid & 7) * (NBLK / 8) + (bid >> 3);
    const int q3   = sbid / 3;
    const int r3   = sbid - q3 * 3;

    if (r3 == 2) {
        // ---- copy block: out[:,0] = voxels[:,0] ----
        int t4 = q3 * 256 + tid;                        // [0, 2^21)
        int b  = t4 >> 20;
        int rr = t4 & ((1 << 20) - 1);
        size_t base = (size_t)(b * TT) * CCH * G3_;
        const float4* s = (const float4*)(vox + base);
        float4* d = (float4*)(out + base);
        d[rr] = s[rr];
        return;
    }

    // ---- warp block: tile t9, channel group cg ----
    const int wid = q3 * 2 + r3;                        // [0, 16384)
    const int cg  = wid >> 12;                          // channel group [0,4)
    const int t9  = wid & 4095;                         // tile id
    const int n   = t9 >> 9;                            // pose [0,8)
    const int t6  = t9 & 511;
    const int ox  = (t6 & 7) << 3;
    const int oy  = ((t6 >> 3) & 7) << 3;
    const int oz  = (t6 >> 6) << 3;
    const int b   = n >> 2, j = n & 3;

    // precomputed affine coefficients (block-uniform)
    const float* Cp = Tc + n * 12;
    const float ax = Cp[0], bx = Cp[1], cx = Cp[2];
    const float ay = Cp[3], by = Cp[4], cy = Cp[5];
    const float az = Cp[6], bz = Cp[7], cz = Cp[8];
    const float kx = Cp[9], ky = Cp[10], kz = Cp[11];

    // bbox of sample coords over the tile (affine -> extrema at corners)
    float x0a = ax * ox, x0b = ax * (ox + 7);
    float x1a = bx * oy, x1b = bx * (oy + 7);
    float x2a = cx * oz, x2b = cx * (oz + 7);
    float min_ix = kx + fminf(x0a, x0b) + fminf(x1a, x1b) + fminf(x2a, x2b);
    float max_ix = kx + fmaxf(x0a, x0b) + fmaxf(x1a, x1b) + fmaxf(x2a, x2b);
    float y0a = ay * ox, y0b = ay * (ox + 7);
    float y1a = by * oy, y1b = by * (oy + 7);
    float y2a = cy * oz, y2b = cy * (oz + 7);
    float min_iy = ky + fminf(y0a, y0b) + fminf(y1a, y1b) + fminf(y2a, y2b);
    float max_iy = ky + fmaxf(y0a, y0b) + fmaxf(y1a, y1b) + fmaxf(y2a, y2b);
    float z0a = az * ox, z0b = az * (ox + 7);
    float z1a = bz * oy, z1b = bz * (oy + 7);
    float z2a = cz * oz, z2b = cz * (oz + 7);
    float min_iz = kz + fminf(z0a, z0b) + fminf(z1a, z1b) + fminf(z2a, z2b);
    float max_iz = kz + fmaxf(z0a, z0b) + fmaxf(z1a, z1b) + fmaxf(z2a, z2b);

    int xlo = min(max((int)floorf(min_ix), 0), 63);
    int xhi = min(max((int)floorf(max_ix) + 1, 0), 63);
    int ylo = min(max((int)floorf(min_iy), 0), 63);
    int yhi = min(max((int)floorf(max_iy) + 1, 0), 63);
    int zlo = min(max((int)floorf(min_iz), 0), 63);
    int zhi = min(max((int)floorf(max_iz) + 1, 0), 63);
    const int xlo_e = xlo & ~1;          // even-align for float2 staging
    const int sxe = xhi - xlo_e + 1;     // <= 16
    const int sy  = yhi - ylo + 1;       // <= 15
    const int sz  = zhi - zlo + 1;       // <= 15
    const int lstep = sy * LSTRIDE;

    // per-thread interp setup (channel-invariant). Each thread owns the
    // x-adjacent output pair (gx0, gx0+1): 2nd sample pos = 1st + (ax,ay,az).
    const int gx0 = ox + ((tid & 3) << 1);
    const int gy  = oy + ((tid >> 2) & 7);
    const int gz  = oz + (tid >> 5);
    const float ix0 = kx + ax * gx0 + bx * gy + cx * gz;
    const float iy0 = ky + ay * gx0 + by * gy + cy * gz;
    const float iz0 = kz + az * gx0 + bz * gy + cz * gz;

    float wx0[2], wx1[2], wy0[2], wy1[2], wz0[2], wz1[2];
    int base0[2], base1[2];
    #pragma unroll
    for (int k = 0; k < 2; ++k) {
        float ix = ix0 + (k ? ax : 0.0f);
        float iy = iy0 + (k ? ay : 0.0f);
        float iz = iz0 + (k ? az : 0.0f);
        float fx = floorf(ix), fy = floorf(iy), fz = floorf(iz);
        float tx = ix - fx, ty = iy - fy, tz = iz - fz;
        int X0 = (int)fx, Y0 = (int)fy, Z0 = (int)fz;

        float w0 = ((unsigned)X0 < 64u) ? (1.0f - tx) : 0.0f;
        float w1 = ((unsigned)(X0 + 1) < 64u) ? tx : 0.0f;
        int rxu = X0 - xlo_e;
        // X0==-1: low corner invalid, high valid at col 0 -> swap weights.
        wx0[k] = (rxu < 0) ? w1 : w0;
        wx1[k] = (rxu < 0) ? 0.0f : w1;
        int rx0 = min(max(rxu, 0), sxe - 1);

        w0 = ((unsigned)Y0 < 64u) ? (1.0f - ty) : 0.0f;
        w1 = ((unsigned)(Y0 + 1) < 64u) ? ty : 0.0f;
        int ryu = Y0 - ylo;
        wy0[k] = (ryu < 0) ? w1 : w0;
        wy1[k] = (ryu < 0) ? 0.0f : w1;
        int ry0 = min(max(ryu, 0), sy - 1);

        wz0[k] = ((unsigned)Z0 < 64u) ? (1.0f - tz) : 0.0f;
        wz1[k] = ((unsigned)(Z0 + 1) < 64u) ? tz : 0.0f;
        int rz0 = min(max(Z0     - zlo, 0), sz - 1);
        int rz1 = min(max(Z0 + 1 - zlo, 0), sz - 1);

        base0[k] = rz0 * lstep + ry0 * LSTRIDE + rx0;   // + {0,1,17,18}
        base1[k] = rz1 * lstep + ry0 * LSTRIDE + rx0;
    }
    const int soff = (gz << 12) + (gy << 6) + gx0;      // float2-aligned

    // channel-group base: channels [cg*NCHB, cg*NCHB + NCHB)
    const size_t fb = ((size_t)(b * TT + j + 1) * CCH + cg * NCHB) * G3_;
    const float* vbase = vox + fb;
    float* obase = out + fb;

    // staging: 8 even x-pairs (float2) x 16 y-rows; z split across the
    // two half-blocks (zh). xe even <= 62 -> xe+1 <= 63: never leaves row.
    const int lane8 = tid & 7;
    const int row16 = (tid >> 3) & 15;
    const int zh    = tid >> 7;                         // 0/1
    const int xe    = xlo_e + (lane8 << 1);
    const bool actS = (xe <= xhi) && (row16 < sy);
    const int grow  = (zlo << 12) + ((ylo + row16) << 6) + xe;
    const int lrow  = row16 * LSTRIDE + (lane8 << 1);

    // 2-deep prefetch registers (ping-pong).
    float2 stgA[8], stgB[8];

    // prologue: issue ch0 (A) and ch1 (B) loads, minimal zero-init, write A
    // after vmcnt(8), ONE barrier, start interp.
    if (actS) {
        const float2* gp = (const float2*)(vbase + grow);
        #pragma unroll
        for (int k = 0; k < 8; ++k) {
            int zz = (k << 1) + zh;
            if (zz < sz) stgA[k] = gp[(size_t)zz << 11];
        }
        if (NCHB > 1) {
            const float2* gq = (const float2*)(vbase + (size_t)G3_ + grow);
            #pragma unroll
            for (int k = 0; k < 8; ++k) {
                int zz = (k << 1) + zh;
                if (zz < sz) stgB[k] = gq[(size_t)zz << 11];
            }
        }
    }

    // MINIMAL zero-init: exactly the weight-0-reachable unstaged slots.
    //  (a) col sxe of each staged row: reads base+1/+18 with clamped rx0.
    //  (b) tail [sz*lstep, sz*lstep+17): reads +17/+18 off the last slab's
    //      clamped last row. (Non-weight-0 reads provably stay staged:
    //      X0 <= xhi-1 when wx1 != 0, analogously y/z.)
    // Benign race with staging writes at col sxe (sxe odd): both finite,
    // slot only read with weight 0.
    {
        int rz = tid >> 4, ry = tid & 15;
        if (rz < sz && ry < sy) lds[rz * lstep + ry * LSTRIDE + sxe] = 0.0f;
        if (tid < 17) lds[sz * lstep + tid] = 0.0f;
    }
    if (actS) {
        #pragma unroll
        for (int k = 0; k < 8; ++k) {
            int zz = (k << 1) + zh;
            if (zz < sz) {
                float* wp = lds + lrow + zz * lstep;
                wp[0] = stgA[k].x;
                wp[1] = stgA[k].y;
            }
        }
    }
    __syncthreads();

    #pragma unroll
    for (int cc = 0; cc < NCHB; ++cc) {
        // (1) issue global loads for channel cc+2 into the freed buffer.
        if (cc + 2 < NCHB && actS) {
            const float2* gp = (const float2*)(vbase + (size_t)(cc + 2) * G3_ + grow);
            #pragma unroll
            for (int k = 0; k < 8; ++k) {
                int zz = (k << 1) + zh;
                if (zz < sz) { if ((cc & 1) == 0) stgA[k] = gp[(size_t)zz << 11];
                               else               stgB[k] = gp[(size_t)zz << 11]; }
            }
        }

        // (2) interpolate channel cc: 4x ds_read2_b32 per output, one fused
        // float2 store for the x-adjacent pair.
        float* op = obase + (size_t)cc * G3_;
        float res[2];
        #pragma unroll
        for (int k = 0; k < 2; ++k) {
            const float* pz0 = lds + base0[k];
            const float* pz1 = lds + base1[k];
            float v000 = pz0[0],  v001 = pz0[1];
            float v010 = pz0[17], v011 = pz0[18];
            float v100 = pz1[0],  v101 = pz1[1];
            float v110 = pz1[17], v111 = pz1[18];
            float t00 = v000 * wx0[k] + v001 * wx1[k];
            float t01 = v010 * wx0[k] + v011 * wx1[k];
            float t10 = v100 * wx0[k] + v101 * wx1[k];
            float t11 = v110 * wx0[k] + v111 * wx1[k];
            float u0  = t00 * wy0[k] + t01 * wy1[k];
            float u1  = t10 * wy0[k] + t11 * wy1[k];
            res[k] = u0 * wz0[k] + u1 * wz1[k];
        }
        *(float2*)(op + soff) = make_float2(res[0], res[1]);

        // (3) handoff: barrier (reads of cc done), write ch cc+1 from the
        // older prefetch buffer (compiler waits vmcnt(8): cc+2's loads stay
        // in flight), barrier (writes visible).
        if (cc + 1 < NCHB) {
            __syncthreads();
            if (actS) {
                #pragma unroll
                for (int k = 0; k < 8; ++k) {
                    int zz = (k << 1) + zh;
                    if (zz < sz) {
                        float* wp = lds + lrow + zz * lstep;
                        float2 v = ((cc & 1) == 0) ? stgB[k] : stgA[k];
                        wp[0] = v.x;
                        wp[1] = v.y;
                    }
                }
            }
            __syncthreads();
        }
    }
}

extern "C" void kernel_launch(void* const* d_in, const int* in_sizes, int n_in,
                              void* d_out, int out_size, void* d_ws, size_t ws_size,
                              hipStream_t stream)
{
    const float* vox = (const float*)d_in[0];
    const float* cam = (const float*)d_in[1];
    float* out = (float*)d_out;
    float* Tc  = (float*)d_ws;          // 8 poses * 12 floats

    hipLaunchKernelGGL(coeff_kernel, dim3(1), dim3(64), 0, stream, cam, Tc);
    hipLaunchKernelGGL(fused_kernel, dim3(NBLK), dim3(256), 0, stream, vox, Tc, out);
}

// Round 9
// 344.788 us; speedup vs baseline: 1.0490x; 1.0490x over previous
//
#include <hip/hip_runtime.h>

// Problem constants: B=2, t=5, C=16, G=64
#define G3_    (64 * 64 * 64)          // 262144
#define CCH    16
#define TT     5
#define LSTRIDE 17                      // padded LDS x-stride (cols 0..16)
#define BUF    4096                     // floats: single LDS buffer (max idx 3841)
#define NCHB   2                        // channels per warp block (round-9: TLP lever)
#define NWARP  (4096 * (CCH / NCHB))    // 32768 warp blocks (tile x channel-group)
#define NCOPY  8192
#define NBLK   (NWARP + NCOPY)          // 40960 = 8 * 5120

// ---------------------------------------------------------------------------
// Round-9: NCHB 4 -> 2 (the pre-committed TLP move).
// Elimination from rounds 1-8: not VALU instr count (r7 hoist/x-pair: 0),
// not LDS instr count (r8 minimal zero-init: 0), not vmcnt drain depth
// (r8 2-deep prefetch: 0), not occupancy-via-regcap (r1: spill), not HBM
// (22%). The only lever that moved time was BLOCK-LEVEL TLP (r3: 4x blocks
// -> 198->156; r4 inverse: half blocks -> 254). The kernel is bound by
// per-block serial chain latency; more independent resident blocks is the
// only coverage. NCHB=2: 32768 warp blocks, chain = 2 channels, 3 barriers
// per block (vs 7). Aggregate VALU rises ~1.5x (setup duplicated) but the
// VALU floor (~87us equiv) stays below current 157us -> headroom.
// Reverted: 2-deep prefetch (r8: neutral, cost occupancy). Kept: minimal
// zero-init (proof in r8 comment), single-register prefetch, x-pair outputs
// + fused float2 store, ds_read2 corner reads + low-edge weight swap,
// even-aligned float2 staging, hoisted coeff kernel, XCD swizzle.
// Interleave now 4 warp : 1 copy (40960 = 5 * 8192).
// ---------------------------------------------------------------------------

// Setup kernel: per pose n -> {ax,bx,cx, ay,by,cy, az,bz,cz, kx,ky,kz}.
__global__ void coeff_kernel(const float* __restrict__ cam, float* __restrict__ Tc)
{
    int n = threadIdx.x;
    if (n >= 8) return;
    int b = n >> 2, j = n & 3;
    const float* p0 = cam + (size_t)(b * TT) * 16;
    const float* p1 = cam + (size_t)(b * TT + j + 1) * 16;
    float a00 = p0[0], a01 = p0[1], a02 = p0[2],  at0 = p0[3];
    float a10 = p0[4], a11 = p0[5], a12 = p0[6],  at1 = p0[7];
    float a20 = p0[8], a21 = p0[9], a22 = p0[10], at2 = p0[11];
    float b00 = p1[0], b01 = p1[1], b02 = p1[2],  bt0 = p1[3];
    float b10 = p1[4], b11 = p1[5], b12 = p1[6],  bt1 = p1[7];
    float b20 = p1[8], b21 = p1[9], b22 = p1[10], bt2 = p1[11];
    // T = P0 * inv(P1), rigid: R = R0*R1^T, tr = t0 - R*t1.
    float R00 = a00*b00 + a01*b01 + a02*b02;
    float R01 = a00*b10 + a01*b11 + a02*b12;
    float R02 = a00*b20 + a01*b21 + a02*b22;
    float R10 = a10*b00 + a11*b01 + a12*b02;
    float R11 = a10*b10 + a11*b11 + a12*b12;
    float R12 = a10*b20 + a11*b21 + a12*b22;
    float R20 = a20*b00 + a21*b01 + a22*b02;
    float R21 = a20*b10 + a21*b11 + a22*b12;
    float R22 = a20*b20 + a21*b21 + a22*b22;
    float trx = at0 - (R00*bt0 + R01*bt1 + R02*bt2);
    float try_= at1 - (R10*bt0 + R11*bt1 + R12*bt2);
    float trz = at2 - (R20*bt0 + R21*bt1 + R22*bt2);

    const float S  = 1.0f / 64.0f;
    const float SC = 32.0f / 0.4921875f;
    float ax = SC * R00 * S, bx = SC * R01 * S, cx = SC * R02 * S;
    float ay = SC * R10 * S, by = SC * R11 * S, cy = SC * R12 * S;
    float az = SC * R20 * S, bz = SC * R21 * S, cz = SC * R22 * S;
    float* o = Tc + n * 12;
    o[0] = ax; o[1] = bx; o[2] = cx;
    o[3] = ay; o[4] = by; o[5] = cy;
    o[6] = az; o[7] = bz; o[8] = cz;
    o[9]  = -31.5f * (ax + bx + cx) + SC * trx + 31.5f;
    o[10] = -31.5f * (ay + by + cy) + SC * try_ + 31.5f;
    o[11] = -31.5f * (az + bz + cz) + SC * trz + 31.5f;
}

__global__ __launch_bounds__(256) void fused_kernel(const float* __restrict__ vox,
                                                    const float* __restrict__ Tc,
                                                    float* __restrict__ out)
{
    __shared__ float lds[BUF];                          // 16 KB
    const int tid = threadIdx.x;

    // XCD-contiguous bijective swizzle (40960 % 8 == 0).
    const int bid  = blockIdx.x;
    const int sbid = (bid & 7) * (NBLK / 8) + (bid >> 3);
    const int q5   = sbid / 5;
    const int r5   = sbid - q5 * 5;

    if (r5 == 4) {
        // ---- copy block: out[:,0] = voxels[:,0] ----
        int t4 = q5 * 256 + tid;                        // [0, 2^21)
        int b  = t4 >> 20;
        int rr = t4 & ((1 << 20) - 1);
        size_t base = (size_t)(b * TT) * CCH * G3_;
        const float4* s = (const float4*)(vox + base);
        float4* d = (float4*)(out + base);
        d[rr] = s[rr];
        return;
    }

    // ---- warp block: tile t9, channel group cg ----
    const int wid = q5 * 4 + r5;                        // [0, 32768)
    const int cg  = wid >> 12;                          // channel group [0,8)
    const int t9  = wid & 4095;                         // tile id
    const int n   = t9 >> 9;                            // pose [0,8)
    const int t6  = t9 & 511;
    const int ox  = (t6 & 7) << 3;
    const int oy  = ((t6 >> 3) & 7) << 3;
    const int oz  = (t6 >> 6) << 3;
    const int b   = n >> 2, j = n & 3;

    // precomputed affine coefficients (block-uniform)
    const float* Cp = Tc + n * 12;
    const float ax = Cp[0], bx = Cp[1], cx = Cp[2];
    const float ay = Cp[3], by = Cp[4], cy = Cp[5];
    const float az = Cp[6], bz = Cp[7], cz = Cp[8];
    const float kx = Cp[9], ky = Cp[10], kz = Cp[11];

    // bbox of sample coords over the tile (affine -> extrema at corners)
    float x0a = ax * ox, x0b = ax * (ox + 7);
    float x1a = bx * oy, x1b = bx * (oy + 7);
    float x2a = cx * oz, x2b = cx * (oz + 7);
    float min_ix = kx + fminf(x0a, x0b) + fminf(x1a, x1b) + fminf(x2a, x2b);
    float max_ix = kx + fmaxf(x0a, x0b) + fmaxf(x1a, x1b) + fmaxf(x2a, x2b);
    float y0a = ay * ox, y0b = ay * (ox + 7);
    float y1a = by * oy, y1b = by * (oy + 7);
    float y2a = cy * oz, y2b = cy * (oz + 7);
    float min_iy = ky + fminf(y0a, y0b) + fminf(y1a, y1b) + fminf(y2a, y2b);
    float max_iy = ky + fmaxf(y0a, y0b) + fmaxf(y1a, y1b) + fmaxf(y2a, y2b);
    float z0a = az * ox, z0b = az * (ox + 7);
    float z1a = bz * oy, z1b = bz * (oy + 7);
    float z2a = cz * oz, z2b = cz * (oz + 7);
    float min_iz = kz + fminf(z0a, z0b) + fminf(z1a, z1b) + fminf(z2a, z2b);
    float max_iz = kz + fmaxf(z0a, z0b) + fmaxf(z1a, z1b) + fmaxf(z2a, z2b);

    int xlo = min(max((int)floorf(min_ix), 0), 63);
    int xhi = min(max((int)floorf(max_ix) + 1, 0), 63);
    int ylo = min(max((int)floorf(min_iy), 0), 63);
    int yhi = min(max((int)floorf(max_iy) + 1, 0), 63);
    int zlo = min(max((int)floorf(min_iz), 0), 63);
    int zhi = min(max((int)floorf(max_iz) + 1, 0), 63);
    const int xlo_e = xlo & ~1;          // even-align for float2 staging
    const int sxe = xhi - xlo_e + 1;     // <= 16
    const int sy  = yhi - ylo + 1;       // <= 15
    const int sz  = zhi - zlo + 1;       // <= 15
    const int lstep = sy * LSTRIDE;

    // per-thread interp setup (channel-invariant). Each thread owns the
    // x-adjacent output pair (gx0, gx0+1): 2nd sample pos = 1st + (ax,ay,az).
    const int gx0 = ox + ((tid & 3) << 1);
    const int gy  = oy + ((tid >> 2) & 7);
    const int gz  = oz + (tid >> 5);
    const float ix0 = kx + ax * gx0 + bx * gy + cx * gz;
    const float iy0 = ky + ay * gx0 + by * gy + cy * gz;
    const float iz0 = kz + az * gx0 + bz * gy + cz * gz;

    float wx0[2], wx1[2], wy0[2], wy1[2], wz0[2], wz1[2];
    int base0[2], base1[2];
    #pragma unroll
    for (int k = 0; k < 2; ++k) {
        float ix = ix0 + (k ? ax : 0.0f);
        float iy = iy0 + (k ? ay : 0.0f);
        float iz = iz0 + (k ? az : 0.0f);
        float fx = floorf(ix), fy = floorf(iy), fz = floorf(iz);
        float tx = ix - fx, ty = iy - fy, tz = iz - fz;
        int X0 = (int)fx, Y0 = (int)fy, Z0 = (int)fz;

        float w0 = ((unsigned)X0 < 64u) ? (1.0f - tx) : 0.0f;
        float w1 = ((unsigned)(X0 + 1) < 64u) ? tx : 0.0f;
        int rxu = X0 - xlo_e;
        // X0==-1: low corner invalid, high valid at col 0 -> swap weights.
        wx0[k] = (rxu < 0) ? w1 : w0;
        wx1[k] = (rxu < 0) ? 0.0f : w1;
        int rx0 = min(max(rxu, 0), sxe - 1);

        w0 = ((unsigned)Y0 < 64u) ? (1.0f - ty) : 0.0f;
        w1 = ((unsigned)(Y0 + 1) < 64u) ? ty : 0.0f;
        int ryu = Y0 - ylo;
        wy0[k] = (ryu < 0) ? w1 : w0;
        wy1[k] = (ryu < 0) ? 0.0f : w1;
        int ry0 = min(max(ryu, 0), sy - 1);

        wz0[k] = ((unsigned)Z0 < 64u) ? (1.0f - tz) : 0.0f;
        wz1[k] = ((unsigned)(Z0 + 1) < 64u) ? tz : 0.0f;
        int rz0 = min(max(Z0     - zlo, 0), sz - 1);
        int rz1 = min(max(Z0 + 1 - zlo, 0), sz - 1);

        base0[k] = rz0 * lstep + ry0 * LSTRIDE + rx0;   // + {0,1,17,18}
        base1[k] = rz1 * lstep + ry0 * LSTRIDE + rx0;
    }
    const int soff = (gz << 12) + (gy << 6) + gx0;      // float2-aligned

    // channel-group base: channels [cg*NCHB, cg*NCHB + NCHB)
    const size_t fb = ((size_t)(b * TT + j + 1) * CCH + cg * NCHB) * G3_;
    const float* vbase = vox + fb;
    float* obase = out + fb;

    // staging: 8 even x-pairs (float2) x 16 y-rows; z split across the
    // two half-blocks (zh). xe even <= 62 -> xe+1 <= 63: never leaves row.
    const int lane8 = tid & 7;
    const int row16 = (tid >> 3) & 15;
    const int zh    = tid >> 7;                         // 0/1
    const int xe    = xlo_e + (lane8 << 1);
    const bool actS = (xe <= xhi) && (row16 < sy);
    const int grow  = (zlo << 12) + ((ylo + row16) << 6) + xe;
    const int lrow  = row16 * LSTRIDE + (lane8 << 1);

    float2 stg[8];

    // prologue: issue ch0 loads FIRST, minimal zero-init under the load
    // latency, write ch0, ONE barrier, start interp.
    if (actS) {
        const float2* gp = (const float2*)(vbase + grow);
        #pragma unroll
        for (int k = 0; k < 8; ++k) {
            int zz = (k << 1) + zh;
            if (zz < sz) stg[k] = gp[(size_t)zz << 11];
        }
    }

    // MINIMAL zero-init: exactly the weight-0-reachable unstaged slots.
    //  (a) col sxe of each staged row: reads base+1/+18 with clamped rx0.
    //  (b) tail [sz*lstep, sz*lstep+17): reads +17/+18 off the last slab's
    //      clamped last row. (Non-weight-0 reads provably stay staged:
    //      X0 <= xhi-1 when wx1 != 0, analogously y/z.) Benign race with
    //      staging writes at col sxe: both finite, slot read at weight 0.
    {
        int rz = tid >> 4, ry = tid & 15;
        if (rz < sz && ry < sy) lds[rz * lstep + ry * LSTRIDE + sxe] = 0.0f;
        if (tid < 17) lds[sz * lstep + tid] = 0.0f;
    }
    if (actS) {
        #pragma unroll
        for (int k = 0; k < 8; ++k) {
            int zz = (k << 1) + zh;
            if (zz < sz) {
                float* wp = lds + lrow + zz * lstep;
                wp[0] = stg[k].x;
                wp[1] = stg[k].y;
            }
        }
    }
    __syncthreads();

    #pragma unroll
    for (int cc = 0; cc < NCHB; ++cc) {
        // (1) issue global float2 loads for channel cc+1 — no wait.
        const bool pre = (cc + 1 < NCHB);
        if (pre && actS) {
            const float2* gp = (const float2*)(vbase + (size_t)(cc + 1) * G3_ + grow);
            #pragma unroll
            for (int k = 0; k < 8; ++k) {
                int zz = (k << 1) + zh;
                if (zz < sz) stg[k] = gp[(size_t)zz << 11];   // sz uniform
            }
        }

        // (2) interpolate channel cc: 4x ds_read2_b32 per output, one fused
        // float2 store for the x-adjacent pair.
        float* op = obase + (size_t)cc * G3_;
        float res[2];
        #pragma unroll
        for (int k = 0; k < 2; ++k) {
            const float* pz0 = lds + base0[k];
            const float* pz1 = lds + base1[k];
            float v000 = pz0[0],  v001 = pz0[1];
            float v010 = pz0[17], v011 = pz0[18];
            float v100 = pz1[0],  v101 = pz1[1];
            float v110 = pz1[17], v111 = pz1[18];
            float t00 = v000 * wx0[k] + v001 * wx1[k];
            float t01 = v010 * wx0[k] + v011 * wx1[k];
            float t10 = v100 * wx0[k] + v101 * wx1[k];
            float t11 = v110 * wx0[k] + v111 * wx1[k];
            float u0  = t00 * wy0[k] + t01 * wy1[k];
            float u1  = t10 * wy0[k] + t11 * wy1[k];
            res[k] = u0 * wz0[k] + u1 * wz1[k];
        }
        *(float2*)(op + soff) = make_float2(res[0], res[1]);

        // (3) handoff: barrier (reads of cc done), write cc+1, barrier
        // (writes visible). Cross-block TLP covers these stalls.
        if (pre) {
            __syncthreads();
            if (actS) {
                #pragma unroll
                for (int k = 0; k < 8; ++k) {
                    int zz = (k << 1) + zh;
                    if (zz < sz) {
                        float* wp = lds + lrow + zz * lstep;
                        wp[0] = stg[k].x;
                        wp[1] = stg[k].y;
                    }
                }
            }
            __syncthreads();
        }
    }
}

extern "C" void kernel_launch(void* const* d_in, const int* in_sizes, int n_in,
                              void* d_out, int out_size, void* d_ws, size_t ws_size,
                              hipStream_t stream)
{
    const float* vox = (const float*)d_in[0];
    const float* cam = (const float*)d_in[1];
    float* out = (float*)d_out;
    float* Tc  = (float*)d_ws;          // 8 poses * 12 floats

    hipLaunchKernelGGL(coeff_kernel, dim3(1), dim3(64), 0, stream, cam, Tc);
    hipLaunchKernelGGL(fused_kernel, dim3(NBLK), dim3(256), 0, stream, vox, Tc, out);
}